// Round 5
// baseline (256.427 us; speedup 1.0000x reference)
//
#include <hip/hip_runtime.h>
#include <math.h>

// ---------------------------------------------------------------------------
// CNE: 2-layer GCN (PyG GCNConv norm w/ self loops) + outcome/propensity heads
// N=100000, E=1600000, IN=128, H=64, T=C=20000.
//
// R5: layer-2 aggregation fused with propensity head (Wp1 staged in LDS,
// row broadcast via LDS; kills k_tprob's 25.6MB re-read). Agg gather loop
// deepened to 16 loads in flight. R4 structure otherwise.
// ---------------------------------------------------------------------------

#define CHUNK 16384  // edges per binning block
#define BSH 7        // 128 dst nodes per bucket

typedef __attribute__((ext_vector_type(8))) _Float16 half8;
typedef __attribute__((ext_vector_type(4))) float f32x4;

__device__ __forceinline__ float wave_sum64(float v) {
#pragma unroll
  for (int m = 32; m >= 1; m >>= 1) v += __shfl_xor(v, m, 64);
  return v;
}

__device__ __forceinline__ float lrelu(float x) { return x > 0.0f ? x : 0.01f * x; }

// ---- bucket histogram per chunk (LDS only) ----
__global__ void k_count(const int* __restrict__ dst, int E, int nbuck,
                        int* __restrict__ bcount, int* __restrict__ blkcount) {
  __shared__ int bh[1024];
  int t = threadIdx.x;
  for (int i = t; i < nbuck; i += 256) bh[i] = 0;
  __syncthreads();
  int e0 = blockIdx.x * CHUNK;
  int e1 = min(e0 + CHUNK, E);
  for (int e = e0 + t; e < e1; e += 256) atomicAdd(&bh[dst[e] >> BSH], 1);
  __syncthreads();
  for (int i = t; i < nbuck; i += 256) {
    int c = bh[i];
    blkcount[blockIdx.x * nbuck + i] = c;
    if (c) atomicAdd(&bcount[i], c);
  }
}

// ---- exclusive scan of bucket counts (nbuck <= 1024), one block ----
__global__ void k_scan1(const int* __restrict__ bcount, int* __restrict__ bbase, int nbuck) {
  __shared__ int s[1024];
  int t = threadIdx.x;
  int v = (t < nbuck) ? bcount[t] : 0;
  s[t] = v;
  __syncthreads();
  for (int off = 1; off < 1024; off <<= 1) {
    int u = (t >= off) ? s[t - off] : 0;
    __syncthreads();
    s[t] += u;
    __syncthreads();
  }
  if (t < nbuck) bbase[t] = s[t] - v;
}

// ---- per-(block,bucket) offsets: column scan over nblk entries ----
__global__ void k_scan2(const int* __restrict__ blkcount, const int* __restrict__ bbase,
                        int* __restrict__ blkoff, int nblk, int nbuck) {
  int lane = threadIdx.x & 63;
  int b = (blockIdx.x * blockDim.x + threadIdx.x) >> 6;  // one wave per bucket
  if (b >= nbuck) return;
  int carry = bbase[b];
  for (int base = 0; base < nblk; base += 64) {
    int i = base + lane;
    int v = (i < nblk) ? blkcount[i * nbuck + b] : 0;
    int x = v;
#pragma unroll
    for (int off = 1; off < 64; off <<= 1) {
      int u = __shfl_up(x, off, 64);
      if (lane >= off) x += u;
    }
    if (i < nblk) blkoff[i * nbuck + b] = carry + (x - v);
    carry += __shfl(x, 63, 64);
  }
}

// ---- binned scatter: pack src (bits 0..19) | (dst & 127) << 20 ----
__global__ void k_bscatter(const int* __restrict__ src, const int* __restrict__ dst,
                           int E, int nbuck, const int* __restrict__ blkoff,
                           unsigned int* __restrict__ pairs) {
  __shared__ int cur[1024];
  int t = threadIdx.x;
  for (int i = t; i < nbuck; i += 256) cur[i] = blkoff[blockIdx.x * nbuck + i];
  __syncthreads();
  int e0 = blockIdx.x * CHUNK;
  int e1 = min(e0 + CHUNK, E);
  for (int e = e0 + t; e < e1; e += 256) {
    int s = src[e];
    int d = dst[e];
    int p = atomicAdd(&cur[d >> BSH], 1);
    pairs[p] = (unsigned int)s | ((unsigned int)(d & 127) << 20);
  }
}

// ---- in-bucket sort -> per-node CSR + degree + dinv ----
__global__ void k_sort(const unsigned int* __restrict__ pairs, const int* __restrict__ bbase,
                       const int* __restrict__ bcount, int* __restrict__ slot,
                       int* __restrict__ offs, int* __restrict__ cntout,
                       float* __restrict__ dinv, int N) {
  __shared__ int hist[128];
  __shared__ int loc[128];
  __shared__ int cur[128];
  int b = blockIdx.x, t = threadIdx.x;
  if (t < 128) hist[t] = 0;
  __syncthreads();
  int start = bbase[b], cnt = bcount[b];
  for (int i = t; i < cnt; i += 256) atomicAdd(&hist[pairs[start + i] >> 20], 1);
  __syncthreads();
  if (t < 128) loc[t] = hist[t];
  __syncthreads();
  for (int off = 1; off < 128; off <<= 1) {
    int u = (t >= off && t < 128) ? loc[t - off] : 0;
    __syncthreads();
    if (t < 128) loc[t] += u;
    __syncthreads();
  }
  if (t < 128) {
    int ex = loc[t] - hist[t];  // exclusive scan
    cur[t] = ex;
    int node = (b << BSH) + t;
    if (node < N) {
      offs[node] = start + ex;
      cntout[node] = hist[t];
      dinv[node] = rsqrtf((float)(hist[t] + 1));
    }
  }
  __syncthreads();
  for (int i = t; i < cnt; i += 256) {
    unsigned int p = pairs[start + i];
    int d = (int)(p >> 20);
    int pos = atomicAdd(&cur[d], 1);
    slot[start + pos] = (int)(p & 0xFFFFFu);
  }
}

// ---- MFMA GEMM: G16 = fp16( dinv * (X @ W) ), X:[N,K] (TIN), W:[K,64] f32 ----
template <int K, typename TIN>
__launch_bounds__(256)
__global__ void k_gemm_mfma(const TIN* __restrict__ X, const float* __restrict__ W,
                            const float* __restrict__ dinv, _Float16* __restrict__ G, int N) {
  constexpr int KST = K / 32;
  int lane = threadIdx.x & 63;
  int wv = threadIdx.x >> 6;
  int lo = lane & 15;   // A row / B,D col (within tile)
  int hi = lane >> 4;   // k-group for A/B; row-group for D

  half8 bfrag[KST][4];
#pragma unroll
  for (int ks = 0; ks < KST; ks++)
#pragma unroll
    for (int ct = 0; ct < 4; ct++)
#pragma unroll
      for (int j = 0; j < 8; j++)
        bfrag[ks][ct][j] = (_Float16)W[(ks * 32 + hi * 8 + j) * 64 + ct * 16 + lo];

  int r0 = (blockIdx.x * 4 + wv) * 16;
  if (r0 >= N) return;

  f32x4 acc[4];
#pragma unroll
  for (int ct = 0; ct < 4; ct++)
#pragma unroll
    for (int j = 0; j < 4; j++) acc[ct][j] = 0.0f;

  int ar = min(r0 + lo, N - 1);
#pragma unroll
  for (int ks = 0; ks < KST; ks++) {
    const TIN* ap = X + (size_t)ar * K + ks * 32 + hi * 8;
    half8 a;
    if constexpr (sizeof(TIN) == 4) {
      const float4* p = (const float4*)ap;
      float4 u = p[0], v = p[1];
      a[0] = (_Float16)u.x; a[1] = (_Float16)u.y; a[2] = (_Float16)u.z; a[3] = (_Float16)u.w;
      a[4] = (_Float16)v.x; a[5] = (_Float16)v.y; a[6] = (_Float16)v.z; a[7] = (_Float16)v.w;
    } else {
      a = *(const half8*)ap;
    }
#pragma unroll
    for (int ct = 0; ct < 4; ct++)
      acc[ct] = __builtin_amdgcn_mfma_f32_16x16x32_f16(a, bfrag[ks][ct], acc[ct], 0, 0, 0);
  }

  float dv[4];
#pragma unroll
  for (int j = 0; j < 4; j++) dv[j] = dinv[min(r0 + hi * 4 + j, N - 1)];
#pragma unroll
  for (int j = 0; j < 4; j++) {
    int rr = r0 + hi * 4 + j;
    if (rr < N) {
#pragma unroll
      for (int ct = 0; ct < 4; ct++)
        G[(size_t)rr * 64 + ct * 16 + lo] = (_Float16)(acc[ct][j] * dv[j]);
    }
  }
}

// ---- gather helper: acc = G[self] + sum over CSR list, 16 loads in flight ----
__device__ __forceinline__ float gather_sum(const _Float16* __restrict__ G,
                                            const int* __restrict__ slot,
                                            int start, int cnt, int self, int lane) {
  float acc0 = (float)G[(size_t)self * 64 + lane];
  float acc1 = 0.f, acc2 = 0.f, acc3 = 0.f;
  int j = 0;
  for (; j + 16 <= cnt; j += 16) {
    int s[16];
#pragma unroll
    for (int u = 0; u < 16; u++) s[u] = slot[start + j + u];
    float v[16];
#pragma unroll
    for (int u = 0; u < 16; u++) v[u] = (float)G[(size_t)s[u] * 64 + lane];
#pragma unroll
    for (int u = 0; u < 16; u += 4) {
      acc0 += v[u + 0];
      acc1 += v[u + 1];
      acc2 += v[u + 2];
      acc3 += v[u + 3];
    }
  }
  for (; j + 4 <= cnt; j += 4) {
    int s[4];
#pragma unroll
    for (int u = 0; u < 4; u++) s[u] = slot[start + j + u];
    float v[4];
#pragma unroll
    for (int u = 0; u < 4; u++) v[u] = (float)G[(size_t)s[u] * 64 + lane];
    acc0 += v[0]; acc1 += v[1]; acc2 += v[2]; acc3 += v[3];
  }
  for (; j < cnt; j++) acc0 += (float)G[(size_t)slot[start + j] * 64 + lane];
  return (acc0 + acc1) + (acc2 + acc3);
}

// ---- layer-1 aggregation: wave per node, fp16 out, relu ----
__global__ void k_agg1(const _Float16* __restrict__ G, const int* __restrict__ offs,
                       const int* __restrict__ count, const int* __restrict__ slot,
                       const float* __restrict__ dinv, const float* __restrict__ bias,
                       _Float16* __restrict__ Out, int N) {
  int lane = threadIdx.x & 63;
  int wid = (blockIdx.x * blockDim.x + threadIdx.x) >> 6;
  if (wid >= N) return;
  int r = __builtin_amdgcn_readfirstlane(wid);
  float acc = gather_sum(G, slot, offs[r], count[r], r, lane);
  float val = fmaxf(bias[lane] + dinv[r] * acc, 0.f);
  Out[(size_t)r * 64 + lane] = (_Float16)val;
}

// ---- layer-2 aggregation fused with propensity head ----
// xZ2[i] = b2 + dinv[i]*(G[i]+sum);  h = lrelu(xZ2[i] @ Wp1 + bp1);
// tprob[i] = lrelu(h @ Wp2 + bp2)
__launch_bounds__(256)
__global__ void k_agg2t(const _Float16* __restrict__ G, const int* __restrict__ offs,
                        const int* __restrict__ count, const int* __restrict__ slot,
                        const float* __restrict__ dinv, const float* __restrict__ bias,
                        const float* __restrict__ Wp1, const float* __restrict__ bp1,
                        const float* __restrict__ Wp2, const float* __restrict__ bp2,
                        float* __restrict__ xZ2, float* __restrict__ tprob, int N) {
  __shared__ float wp1s[64 * 64];
  __shared__ float rowbuf[4][64];
  int t = threadIdx.x, lane = t & 63, w = t >> 6;
  for (int i = t; i < 64 * 64; i += 256) wp1s[i] = Wp1[i];
  __syncthreads();

  int wid = (blockIdx.x * blockDim.x + t) >> 6;
  bool active = wid < N;
  int r = __builtin_amdgcn_readfirstlane(wid);
  float val = 0.f;
  if (active) {
    float acc = gather_sum(G, slot, offs[r], count[r], r, lane);
    val = bias[lane] + dinv[r] * acc;
    xZ2[(size_t)r * 64 + lane] = val;
    rowbuf[w][lane] = val;
  }
  __syncthreads();
  if (!active) return;

  float h = bp1[lane];
#pragma unroll 8
  for (int k = 0; k < 64; k++) h = fmaf(rowbuf[w][k], wp1s[k * 64 + lane], h);
  h = lrelu(h);
  float s0 = wave_sum64(h * Wp2[lane * 2 + 0]);
  float s1 = wave_sum64(h * Wp2[lane * 2 + 1]);
  if (lane == 0) {
    tprob[(size_t)r * 2 + 0] = lrelu(s0 + bp2[0]);
    tprob[(size_t)r * 2 + 1] = lrelu(s1 + bp2[1]);
  }
}

// ---- outcome heads ----
__global__ void k_heads(const float* __restrict__ Z, const int* __restrict__ treat,
                        const int* __restrict__ ctrl, int T, int C,
                        const float* __restrict__ Wy1, const float* __restrict__ by1,
                        const float* __restrict__ Wy0, const float* __restrict__ by0,
                        float* __restrict__ y1, float* __restrict__ yc0,
                        float* __restrict__ y0, float* __restrict__ yc1) {
  int lane = threadIdx.x & 63;
  int wid = (blockIdx.x * blockDim.x + threadIdx.x) >> 6;
  if (wid >= T + C) return;
  bool treated = wid < T;
  int idx = treated ? wid : wid - T;
  int row = treated ? treat[idx] : ctrl[idx];
  row = __builtin_amdgcn_readfirstlane(row);
  float v = Z[(size_t)row * 64 + lane];
  float s1 = wave_sum64(v * Wy1[lane]);
  float s0 = wave_sum64(v * Wy0[lane]);
  if (lane == 0) {
    float a1 = lrelu(s1 + by1[0]);
    float a0 = lrelu(s0 + by0[0]);
    if (treated) { y1[idx] = a1; yc0[idx] = a0; }
    else         { yc1[idx] = a1; y0[idx] = a0; }
  }
}

extern "C" void kernel_launch(void* const* d_in, const int* in_sizes, int n_in,
                              void* d_out, int out_size, void* d_ws, size_t ws_size,
                              hipStream_t stream) {
  const int IN = 128, H = 64;
  const int N = in_sizes[0] / IN;
  const int E = in_sizes[1] / 2;
  const int T = in_sizes[2];
  const int C = in_sizes[3];
  const int nbuck = (N + 127) >> BSH;         // 782
  const int nblk = (E + CHUNK - 1) / CHUNK;   // 98

  const float* x    = (const float*)d_in[0];
  const int*   ei   = (const int*)d_in[1];
  const int*   src  = ei;
  const int*   dst  = ei + E;
  const int*   trt  = (const int*)d_in[2];
  const int*   ctl  = (const int*)d_in[3];
  const float* W1   = (const float*)d_in[4];
  const float* b1   = (const float*)d_in[5];
  const float* W2   = (const float*)d_in[6];
  const float* b2   = (const float*)d_in[7];
  const float* Wy1  = (const float*)d_in[8];
  const float* by1  = (const float*)d_in[9];
  const float* Wy0  = (const float*)d_in[10];
  const float* by0  = (const float*)d_in[11];
  const float* Wp1  = (const float*)d_in[12];
  const float* bp1  = (const float*)d_in[13];
  const float* Wp2  = (const float*)d_in[14];
  const float* bp2  = (const float*)d_in[15];

  float* out   = (float*)d_out;
  float* y1    = out;                          // [T]
  float* yc0   = out + T;                      // [T]
  float* y0    = out + 2 * T;                  // [C]
  float* yc1   = out + 2 * T + C;              // [C]
  float* tprob = out + 2 * T + 2 * C;          // [N,2]
  float* xZ2   = out + 2 * T + 2 * C + 2 * N;  // [N,64]

  // workspace layout (4-byte units)
  int* bcount    = (int*)d_ws;                      // 1024 (zeroed)
  int* bbase     = bcount + 1024;                   // 1024
  int* blkcount  = bbase + 1024;                    // nblk*nbuck
  int* blkoff    = blkcount + (size_t)nblk * nbuck; // nblk*nbuck
  unsigned int* pairs = (unsigned int*)(blkoff + (size_t)nblk * nbuck);  // E
  int* slot      = (int*)(pairs + E);               // E
  int* offs      = slot + E;                        // N
  int* cnt       = offs + N;                        // N
  float* dinv    = (float*)(cnt + N);               // N
  size_t goff = ((size_t)(dinv + N - (float*)d_ws) + 3) & ~(size_t)3;
  _Float16* g16 = (_Float16*)((float*)d_ws + goff);     // N*64 halves
  _Float16* xZ1 = g16 + (size_t)N * 64;                 // N*64 halves

  hipMemsetAsync(bcount, 0, sizeof(int) * 1024, stream);

  k_count<<<nblk, 256, 0, stream>>>(dst, E, nbuck, bcount, blkcount);
  k_scan1<<<1, 1024, 0, stream>>>(bcount, bbase, nbuck);
  k_scan2<<<(nbuck * 64 + 255) / 256, 256, 0, stream>>>(blkcount, bbase, blkoff, nblk, nbuck);
  k_bscatter<<<nblk, 256, 0, stream>>>(src, dst, E, nbuck, blkoff, pairs);
  k_sort<<<nbuck, 256, 0, stream>>>(pairs, bbase, bcount, slot, offs, cnt, dinv, N);

  const int ngemm = (N + 63) / 64;
  const int nagg = (int)(((size_t)N * 64 + 255) / 256);

  // layer 1
  k_gemm_mfma<128, float><<<ngemm, 256, 0, stream>>>(x, W1, dinv, g16, N);
  k_agg1<<<nagg, 256, 0, stream>>>(g16, offs, cnt, slot, dinv, b1, xZ1, N);

  // layer 2 (+ fused propensity head)
  k_gemm_mfma<64, _Float16><<<ngemm, 256, 0, stream>>>(xZ1, W2, dinv, g16, N);
  k_agg2t<<<nagg, 256, 0, stream>>>(g16, offs, cnt, slot, dinv, b2,
                                    Wp1, bp1, Wp2, bp2, xZ2, tprob, N);

  // outcome heads
  k_heads<<<((size_t)(T + C) * 64 + 255) / 256, 256, 0, stream>>>(
      xZ2, trt, ctl, T, C, Wy1, by1, Wy0, by0, y1, yc0, y0, yc1);
}

// Round 6
// 229.781 us; speedup vs baseline: 1.1160x; 1.1160x over previous
//
#include <hip/hip_runtime.h>
#include <math.h>

// ---------------------------------------------------------------------------
// CNE: 2-layer GCN (PyG GCNConv norm w/ self loops) + outcome/propensity heads
// N=100000, E=1600000, IN=128, H=64, T=C=20000.
//
// R6: unfuse tprob (R5 fusion regressed: per-block Wp1 staging = 400MB L2).
//  - agg gather: half2/lane, 2 edges per vmem inst, predicated 16-edge
//    window so low-degree nodes still get full memory-level parallelism.
//  - tprob via MFMA (xZ2@Wp1) + shfl-reduce Wp2 stage.
// ---------------------------------------------------------------------------

#define CHUNK 16384  // edges per binning block
#define BSH 7        // 128 dst nodes per bucket

typedef __attribute__((ext_vector_type(8))) _Float16 half8;
typedef __attribute__((ext_vector_type(2))) _Float16 half2v;
typedef __attribute__((ext_vector_type(4))) float f32x4;

__device__ __forceinline__ float lrelu(float x) { return x > 0.0f ? x : 0.01f * x; }

__device__ __forceinline__ float wave_sum64(float v) {
#pragma unroll
  for (int m = 32; m >= 1; m >>= 1) v += __shfl_xor(v, m, 64);
  return v;
}

// ---- bucket histogram per chunk (LDS only) ----
__global__ void k_count(const int* __restrict__ dst, int E, int nbuck,
                        int* __restrict__ bcount, int* __restrict__ blkcount) {
  __shared__ int bh[1024];
  int t = threadIdx.x;
  for (int i = t; i < nbuck; i += 256) bh[i] = 0;
  __syncthreads();
  int e0 = blockIdx.x * CHUNK;
  int e1 = min(e0 + CHUNK, E);
  for (int e = e0 + t; e < e1; e += 256) atomicAdd(&bh[dst[e] >> BSH], 1);
  __syncthreads();
  for (int i = t; i < nbuck; i += 256) {
    int c = bh[i];
    blkcount[blockIdx.x * nbuck + i] = c;
    if (c) atomicAdd(&bcount[i], c);
  }
}

// ---- exclusive scan of bucket counts (nbuck <= 1024), one block ----
__global__ void k_scan1(const int* __restrict__ bcount, int* __restrict__ bbase, int nbuck) {
  __shared__ int s[1024];
  int t = threadIdx.x;
  int v = (t < nbuck) ? bcount[t] : 0;
  s[t] = v;
  __syncthreads();
  for (int off = 1; off < 1024; off <<= 1) {
    int u = (t >= off) ? s[t - off] : 0;
    __syncthreads();
    s[t] += u;
    __syncthreads();
  }
  if (t < nbuck) bbase[t] = s[t] - v;
}

// ---- per-(block,bucket) offsets: column scan over nblk entries ----
__global__ void k_scan2(const int* __restrict__ blkcount, const int* __restrict__ bbase,
                        int* __restrict__ blkoff, int nblk, int nbuck) {
  int lane = threadIdx.x & 63;
  int b = (blockIdx.x * blockDim.x + threadIdx.x) >> 6;  // one wave per bucket
  if (b >= nbuck) return;
  int carry = bbase[b];
  for (int base = 0; base < nblk; base += 64) {
    int i = base + lane;
    int v = (i < nblk) ? blkcount[i * nbuck + b] : 0;
    int x = v;
#pragma unroll
    for (int off = 1; off < 64; off <<= 1) {
      int u = __shfl_up(x, off, 64);
      if (lane >= off) x += u;
    }
    if (i < nblk) blkoff[i * nbuck + b] = carry + (x - v);
    carry += __shfl(x, 63, 64);
  }
}

// ---- binned scatter: pack src (bits 0..19) | (dst & 127) << 20 ----
__global__ void k_bscatter(const int* __restrict__ src, const int* __restrict__ dst,
                           int E, int nbuck, const int* __restrict__ blkoff,
                           unsigned int* __restrict__ pairs) {
  __shared__ int cur[1024];
  int t = threadIdx.x;
  for (int i = t; i < nbuck; i += 256) cur[i] = blkoff[blockIdx.x * nbuck + i];
  __syncthreads();
  int e0 = blockIdx.x * CHUNK;
  int e1 = min(e0 + CHUNK, E);
  for (int e = e0 + t; e < e1; e += 256) {
    int s = src[e];
    int d = dst[e];
    int p = atomicAdd(&cur[d >> BSH], 1);
    pairs[p] = (unsigned int)s | ((unsigned int)(d & 127) << 20);
  }
}

// ---- in-bucket sort -> per-node CSR + degree + dinv ----
__global__ void k_sort(const unsigned int* __restrict__ pairs, const int* __restrict__ bbase,
                       const int* __restrict__ bcount, int* __restrict__ slot,
                       int* __restrict__ offs, int* __restrict__ cntout,
                       float* __restrict__ dinv, int N) {
  __shared__ int hist[128];
  __shared__ int loc[128];
  __shared__ int cur[128];
  int b = blockIdx.x, t = threadIdx.x;
  if (t < 128) hist[t] = 0;
  __syncthreads();
  int start = bbase[b], cnt = bcount[b];
  for (int i = t; i < cnt; i += 256) atomicAdd(&hist[pairs[start + i] >> 20], 1);
  __syncthreads();
  if (t < 128) loc[t] = hist[t];
  __syncthreads();
  for (int off = 1; off < 128; off <<= 1) {
    int u = (t >= off && t < 128) ? loc[t - off] : 0;
    __syncthreads();
    if (t < 128) loc[t] += u;
    __syncthreads();
  }
  if (t < 128) {
    int ex = loc[t] - hist[t];  // exclusive scan
    cur[t] = ex;
    int node = (b << BSH) + t;
    if (node < N) {
      offs[node] = start + ex;
      cntout[node] = hist[t];
      dinv[node] = rsqrtf((float)(hist[t] + 1));
    }
  }
  __syncthreads();
  for (int i = t; i < cnt; i += 256) {
    unsigned int p = pairs[start + i];
    int d = (int)(p >> 20);
    int pos = atomicAdd(&cur[d], 1);
    slot[start + pos] = (int)(p & 0xFFFFFu);
  }
}

// ---- MFMA GEMM: G16 = fp16( dinv * (X @ W) ), X:[N,K] (TIN), W:[K,64] f32 ----
template <int K, typename TIN>
__launch_bounds__(256)
__global__ void k_gemm_mfma(const TIN* __restrict__ X, const float* __restrict__ W,
                            const float* __restrict__ dinv, _Float16* __restrict__ G, int N) {
  constexpr int KST = K / 32;
  int lane = threadIdx.x & 63;
  int wv = threadIdx.x >> 6;
  int lo = lane & 15;   // A row / B,D col (within tile)
  int hi = lane >> 4;   // k-group for A/B; row-group for D

  half8 bfrag[KST][4];
#pragma unroll
  for (int ks = 0; ks < KST; ks++)
#pragma unroll
    for (int ct = 0; ct < 4; ct++)
#pragma unroll
      for (int j = 0; j < 8; j++)
        bfrag[ks][ct][j] = (_Float16)W[(ks * 32 + hi * 8 + j) * 64 + ct * 16 + lo];

  int r0 = (blockIdx.x * 4 + wv) * 16;
  if (r0 >= N) return;

  f32x4 acc[4];
#pragma unroll
  for (int ct = 0; ct < 4; ct++)
#pragma unroll
    for (int j = 0; j < 4; j++) acc[ct][j] = 0.0f;

  int ar = min(r0 + lo, N - 1);
#pragma unroll
  for (int ks = 0; ks < KST; ks++) {
    const TIN* ap = X + (size_t)ar * K + ks * 32 + hi * 8;
    half8 a;
    if constexpr (sizeof(TIN) == 4) {
      const float4* p = (const float4*)ap;
      float4 u = p[0], v = p[1];
      a[0] = (_Float16)u.x; a[1] = (_Float16)u.y; a[2] = (_Float16)u.z; a[3] = (_Float16)u.w;
      a[4] = (_Float16)v.x; a[5] = (_Float16)v.y; a[6] = (_Float16)v.z; a[7] = (_Float16)v.w;
    } else {
      a = *(const half8*)ap;
    }
#pragma unroll
    for (int ct = 0; ct < 4; ct++)
      acc[ct] = __builtin_amdgcn_mfma_f32_16x16x32_f16(a, bfrag[ks][ct], acc[ct], 0, 0, 0);
  }

  float dv[4];
#pragma unroll
  for (int j = 0; j < 4; j++) dv[j] = dinv[min(r0 + hi * 4 + j, N - 1)];
#pragma unroll
  for (int j = 0; j < 4; j++) {
    int rr = r0 + hi * 4 + j;
    if (rr < N) {
#pragma unroll
      for (int ct = 0; ct < 4; ct++)
        G[(size_t)rr * 64 + ct * 16 + lo] = (_Float16)(acc[ct][j] * dv[j]);
    }
  }
}

// ---- aggregation: wave per node, half2/lane gather (2 edges per vmem inst),
// predicated 16-edge window for full MLP even at low degree ----
template <typename TOUT>
__launch_bounds__(256)
__global__ void k_agg(const _Float16* __restrict__ G, const int* __restrict__ offs,
                      const int* __restrict__ count, const int* __restrict__ slot,
                      const float* __restrict__ dinv, const float* __restrict__ bias,
                      TOUT* __restrict__ Out, int N, int do_relu) {
  int lane = threadIdx.x & 63;
  int wid = (blockIdx.x * blockDim.x + threadIdx.x) >> 6;
  if (wid >= N) return;
  int r = __builtin_amdgcn_readfirstlane(wid);
  int cp = lane & 31;  // column pair: cols {2cp, 2cp+1}
  int rs = lane >> 5;  // row slot: even/odd edge
  int start = offs[r], cnt = count[r];
  const _Float16* gp = G + 2 * cp;

  float sx = 0.f, sy = 0.f;
  if (rs == 0) {  // self row once
    half2v v = *(const half2v*)(gp + (size_t)r * 64);
    sx += (float)v[0]; sy += (float)v[1];
  }
  for (int j = 0; j < cnt; j += 16) {
    half2v v[8];
    bool a[8];
#pragma unroll
    for (int u = 0; u < 8; u++) {
      int idx = j + 2 * u + rs;
      a[u] = idx < cnt;
      int sidx = min(idx, cnt - 1);
      int e = slot[start + sidx];
      v[u] = *(const half2v*)(gp + (size_t)e * 64);
    }
#pragma unroll
    for (int u = 0; u < 8; u++) {
      if (a[u]) { sx += (float)v[u][0]; sy += (float)v[u][1]; }
    }
  }
  // merge even/odd edge halves
  sx += __shfl_xor(sx, 32, 64);
  sy += __shfl_xor(sy, 32, 64);

  if (rs == 0) {
    float d = dinv[r];
    float bx = bias[2 * cp], by = bias[2 * cp + 1];
    float vx = bx + d * sx;
    float vy = by + d * sy;
    if (do_relu) { vx = fmaxf(vx, 0.f); vy = fmaxf(vy, 0.f); }
    if constexpr (sizeof(TOUT) == 2) {
      half2v o; o[0] = (_Float16)vx; o[1] = (_Float16)vy;
      *(half2v*)((_Float16*)Out + (size_t)r * 64 + 2 * cp) = o;
    } else {
      *(float2*)((float*)Out + (size_t)r * 64 + 2 * cp) = make_float2(vx, vy);
    }
  }
}

// ---- propensity head via MFMA: tprob = lrelu(lrelu(Z@Wp1+bp1)@Wp2+bp2) ----
__launch_bounds__(256)
__global__ void k_tprob_mfma(const float* __restrict__ Z, const float* __restrict__ Wp1,
                             const float* __restrict__ bp1, const float* __restrict__ Wp2,
                             const float* __restrict__ bp2, float* __restrict__ tprob, int N) {
  int lane = threadIdx.x & 63;
  int wv = threadIdx.x >> 6;
  int lo = lane & 15;
  int hi = lane >> 4;

  half8 bfrag[2][4];
#pragma unroll
  for (int ks = 0; ks < 2; ks++)
#pragma unroll
    for (int ct = 0; ct < 4; ct++)
#pragma unroll
      for (int j = 0; j < 8; j++)
        bfrag[ks][ct][j] = (_Float16)Wp1[(ks * 32 + hi * 8 + j) * 64 + ct * 16 + lo];

  int r0 = (blockIdx.x * 4 + wv) * 16;
  if (r0 >= N) return;

  f32x4 acc[4];
#pragma unroll
  for (int ct = 0; ct < 4; ct++)
#pragma unroll
    for (int j = 0; j < 4; j++) acc[ct][j] = 0.0f;

  int ar = min(r0 + lo, N - 1);
#pragma unroll
  for (int ks = 0; ks < 2; ks++) {
    const float4* p = (const float4*)(Z + (size_t)ar * 64 + ks * 32 + hi * 8);
    float4 u = p[0], v = p[1];
    half8 a;
    a[0] = (_Float16)u.x; a[1] = (_Float16)u.y; a[2] = (_Float16)u.z; a[3] = (_Float16)u.w;
    a[4] = (_Float16)v.x; a[5] = (_Float16)v.y; a[6] = (_Float16)v.z; a[7] = (_Float16)v.w;
#pragma unroll
    for (int ct = 0; ct < 4; ct++)
      acc[ct] = __builtin_amdgcn_mfma_f32_16x16x32_f16(a, bfrag[ks][ct], acc[ct], 0, 0, 0);
  }

  float w20[4], w21[4], b1v[4];
#pragma unroll
  for (int ct = 0; ct < 4; ct++) {
    int col = ct * 16 + lo;
    w20[ct] = Wp2[col * 2 + 0];
    w21[ct] = Wp2[col * 2 + 1];
    b1v[ct] = bp1[col];
  }
  float b20 = bp2[0], b21 = bp2[1];

#pragma unroll
  for (int j = 0; j < 4; j++) {
    float t0 = 0.f, t1 = 0.f;
#pragma unroll
    for (int ct = 0; ct < 4; ct++) {
      float h = lrelu(acc[ct][j] + b1v[ct]);
      t0 = fmaf(h, w20[ct], t0);
      t1 = fmaf(h, w21[ct], t1);
    }
#pragma unroll
    for (int m = 1; m <= 8; m <<= 1) {
      t0 += __shfl_xor(t0, m, 64);
      t1 += __shfl_xor(t1, m, 64);
    }
    int rr = r0 + hi * 4 + j;
    if (lo == 0 && rr < N) {
      tprob[(size_t)rr * 2 + 0] = lrelu(t0 + b20);
      tprob[(size_t)rr * 2 + 1] = lrelu(t1 + b21);
    }
  }
}

// ---- outcome heads ----
__global__ void k_heads(const float* __restrict__ Z, const int* __restrict__ treat,
                        const int* __restrict__ ctrl, int T, int C,
                        const float* __restrict__ Wy1, const float* __restrict__ by1,
                        const float* __restrict__ Wy0, const float* __restrict__ by0,
                        float* __restrict__ y1, float* __restrict__ yc0,
                        float* __restrict__ y0, float* __restrict__ yc1) {
  int lane = threadIdx.x & 63;
  int wid = (blockIdx.x * blockDim.x + threadIdx.x) >> 6;
  if (wid >= T + C) return;
  bool treated = wid < T;
  int idx = treated ? wid : wid - T;
  int row = treated ? treat[idx] : ctrl[idx];
  row = __builtin_amdgcn_readfirstlane(row);
  float v = Z[(size_t)row * 64 + lane];
  float s1 = wave_sum64(v * Wy1[lane]);
  float s0 = wave_sum64(v * Wy0[lane]);
  if (lane == 0) {
    float a1 = lrelu(s1 + by1[0]);
    float a0 = lrelu(s0 + by0[0]);
    if (treated) { y1[idx] = a1; yc0[idx] = a0; }
    else         { yc1[idx] = a1; y0[idx] = a0; }
  }
}

extern "C" void kernel_launch(void* const* d_in, const int* in_sizes, int n_in,
                              void* d_out, int out_size, void* d_ws, size_t ws_size,
                              hipStream_t stream) {
  const int IN = 128, H = 64;
  const int N = in_sizes[0] / IN;
  const int E = in_sizes[1] / 2;
  const int T = in_sizes[2];
  const int C = in_sizes[3];
  const int nbuck = (N + 127) >> BSH;         // 782
  const int nblk = (E + CHUNK - 1) / CHUNK;   // 98

  const float* x    = (const float*)d_in[0];
  const int*   ei   = (const int*)d_in[1];
  const int*   src  = ei;
  const int*   dst  = ei + E;
  const int*   trt  = (const int*)d_in[2];
  const int*   ctl  = (const int*)d_in[3];
  const float* W1   = (const float*)d_in[4];
  const float* b1   = (const float*)d_in[5];
  const float* W2   = (const float*)d_in[6];
  const float* b2   = (const float*)d_in[7];
  const float* Wy1  = (const float*)d_in[8];
  const float* by1  = (const float*)d_in[9];
  const float* Wy0  = (const float*)d_in[10];
  const float* by0  = (const float*)d_in[11];
  const float* Wp1  = (const float*)d_in[12];
  const float* bp1  = (const float*)d_in[13];
  const float* Wp2  = (const float*)d_in[14];
  const float* bp2  = (const float*)d_in[15];

  float* out   = (float*)d_out;
  float* y1    = out;                          // [T]
  float* yc0   = out + T;                      // [T]
  float* y0    = out + 2 * T;                  // [C]
  float* yc1   = out + 2 * T + C;              // [C]
  float* tprob = out + 2 * T + 2 * C;          // [N,2]
  float* xZ2   = out + 2 * T + 2 * C + 2 * N;  // [N,64]

  // workspace layout (4-byte units)
  int* bcount    = (int*)d_ws;                      // 1024 (zeroed)
  int* bbase     = bcount + 1024;                   // 1024
  int* blkcount  = bbase + 1024;                    // nblk*nbuck
  int* blkoff    = blkcount + (size_t)nblk * nbuck; // nblk*nbuck
  unsigned int* pairs = (unsigned int*)(blkoff + (size_t)nblk * nbuck);  // E
  int* slot      = (int*)(pairs + E);               // E
  int* offs      = slot + E;                        // N
  int* cnt       = offs + N;                        // N
  float* dinv    = (float*)(cnt + N);               // N
  size_t goff = ((size_t)(dinv + N - (float*)d_ws) + 3) & ~(size_t)3;
  _Float16* g16 = (_Float16*)((float*)d_ws + goff);     // N*64 halves
  _Float16* xZ1 = g16 + (size_t)N * 64;                 // N*64 halves

  hipMemsetAsync(bcount, 0, sizeof(int) * 1024, stream);

  k_count<<<nblk, 256, 0, stream>>>(dst, E, nbuck, bcount, blkcount);
  k_scan1<<<1, 1024, 0, stream>>>(bcount, bbase, nbuck);
  k_scan2<<<(nbuck * 64 + 255) / 256, 256, 0, stream>>>(blkcount, bbase, blkoff, nblk, nbuck);
  k_bscatter<<<nblk, 256, 0, stream>>>(src, dst, E, nbuck, blkoff, pairs);
  k_sort<<<nbuck, 256, 0, stream>>>(pairs, bbase, bcount, slot, offs, cnt, dinv, N);

  const int ngemm = (N + 63) / 64;
  const int nagg = (int)(((size_t)N * 64 + 255) / 256);

  // layer 1
  k_gemm_mfma<128, float><<<ngemm, 256, 0, stream>>>(x, W1, dinv, g16, N);
  k_agg<_Float16><<<nagg, 256, 0, stream>>>(g16, offs, cnt, slot, dinv, b1, xZ1, N, 1);

  // layer 2
  k_gemm_mfma<64, _Float16><<<ngemm, 256, 0, stream>>>(xZ1, W2, dinv, g16, N);
  k_agg<float><<<nagg, 256, 0, stream>>>(g16, offs, cnt, slot, dinv, b2, xZ2, N, 0);

  // heads
  k_tprob_mfma<<<ngemm, 256, 0, stream>>>(xZ2, Wp1, bp1, Wp2, bp2, tprob, N);
  k_heads<<<((size_t)(T + C) * 64 + 255) / 256, 256, 0, stream>>>(
      xZ2, trt, ctl, T, C, Wy1, by1, Wy0, by0, y1, yc0, y0, yc1);
}